// Round 10
// baseline (396.354 us; speedup 1.0000x reference)
//
#include <hip/hip_runtime.h>
#include <math.h>

#define NB 2
#define NN 2048
#define HIDDEN 2048
#define NHEAD 16
#define DHEAD 128

typedef __attribute__((ext_vector_type(8))) short bf16x8;
typedef __attribute__((ext_vector_type(4))) float floatx4;

static __device__ __forceinline__ short f2bf(float f) {
    union { float f; unsigned u; } v; v.f = f;
    unsigned r = v.u + 0x7fffu + ((v.u >> 16) & 1u);
    return (short)(r >> 16);
}
static __device__ __forceinline__ void gload_lds16(const short* g, short* l) {
    __builtin_amdgcn_global_load_lds(
        (const __attribute__((address_space(1))) void*)g,
        (__attribute__((address_space(3))) void*)l, 16, 0, 0);
}

// ---------------------------------------------------------------------------
// cast 3 fp32 arrays to bf16
// ---------------------------------------------------------------------------
__global__ __launch_bounds__(256) void cast_bf16_3(
    const float* __restrict__ a, const float* __restrict__ b, const float* __restrict__ c,
    short* __restrict__ oa, short* __restrict__ ob, short* __restrict__ oc,
    int n4a, int n4b, int n4c)
{
    int i = blockIdx.x * 256 + threadIdx.x;
    const float* s; short* d; int j;
    if (i < n4a) { s = a; d = oa; j = i; }
    else if (i < n4a + n4b) { s = b; d = ob; j = i - n4a; }
    else if (i < n4a + n4b + n4c) { s = c; d = oc; j = i - n4a - n4b; }
    else return;
    float4 v = ((const float4*)s)[j];
    short4 o;
    o.x = f2bf(v.x); o.y = f2bf(v.y); o.z = f2bf(v.z); o.w = f2bf(v.w);
    ((short4*)d)[j] = o;
}

// ---------------------------------------------------------------------------
// QKV GEMM (round-5 verbatim — best measured 141 us): 256x128 tile / BK=64 /
// 8 waves, 2-phase counted-vmcnt pipeline.  Grid (48,16) = 768 = 3 exact
// rounds on 256 CUs.  BN=128 = one head per block.
// ---------------------------------------------------------------------------
__global__ __launch_bounds__(512, 2) void gemm_qkv_256x128(
    const short* __restrict__ A, const short* __restrict__ Bw,
    const float* __restrict__ cosT, const float* __restrict__ sinT,
    short* __restrict__ Qp, short* __restrict__ Kp, short* __restrict__ Vtp)
{
    __shared__ __align__(16) short AB[49152];   // 96 KB

    const int tid = threadIdx.x;
    const int w = tid >> 6;
    const int l = tid & 63;
    const int quad = l >> 4;
    const int l15 = l & 15;
    const int bn = blockIdx.x * 128;
    const int bm = blockIdx.y * 256;
    const int K = HIDDEN;

    // ---- staging sources/dests: 6 loads = A0(2) A1(2) B0(1) B1(1)
    const short* src[6];
    int ldst[6];
#pragma unroll
    for (int ld = 0; ld < 2; ++ld) {
        int chunk = ld * 512 + tid;          // 0..1023 (16B chunks)
        int row = chunk >> 3;                // 0..127
        int j = (chunk & 7) ^ (row & 7);     // inverse swizzle on global src
        int coff = j * 8;
        src[ld]     = A + (size_t)(bm + row) * K + coff;           // A0
        src[2 + ld] = A + (size_t)(bm + 128 + row) * K + coff;     // A1
        ldst[ld]     = chunk * 16;
        ldst[2 + ld] = 16384 + chunk * 16;
    }
    {
        int row = tid >> 3;                  // 0..63
        int j = (tid & 7) ^ (row & 7);
        int coff = j * 8;
        src[4] = Bw + (size_t)(bn + row) * K + coff;               // B0
        src[5] = Bw + (size_t)(bn + 64 + row) * K + coff;          // B1
        ldst[4] = 32768 + tid * 16;
        ldst[5] = 32768 + 8192 + tid * 16;
    }

    // ---- frag-read invariants (frag row&7 == l15&7 everywhere)
    const int xj = l15 & 7;
    const int jq0 = ((0 * 4 + quad) ^ xj) * 16;   // kc=0 chunk byte off
    const int jq1 = ((1 * 4 + quad) ^ xj) * 16;   // kc=1
    const int arow = (w * 32 + l15) * 128;        // + m*2048
    const int brow = 32768 + l15 * 128;           // + n*2048

    floatx4 acc[2][8];
#pragma unroll
    for (int i = 0; i < 2; ++i)
#pragma unroll
        for (int j = 0; j < 8; ++j) acc[i][j] = (floatx4){0.f, 0.f, 0.f, 0.f};

    // ---- prologue: stage tile 0 (A0,A1,B0,B1)
#pragma unroll
    for (int i = 0; i < 6; ++i)
        gload_lds16(src[i], (short*)((char*)AB + ldst[i]));

#define STAGE(i) gload_lds16(src[i] + kpf, (short*)((char*)AB + ldst[i] + so))
#define MFMA(d, x, y) d = __builtin_amdgcn_mfma_f32_16x16x32_bf16(x, y, d, 0, 0, 0)

    const int NT = K / 64;   // 32
#pragma unroll 1
    for (int t = 0; t < NT; ++t) {
        const int co = (t & 1) * 49152;     // compute buffer
        const int so = co ^ 49152;          // stage buffer
        int kpf = (t + 1) * 64;
        if (kpf == K) kpf = 0;              // wrap: dummy prefetch (drained below)

        bf16x8 a[2][2], b[4][2];

        // ---------------- P0: A(m0-1) x B(n0-3)
        asm volatile("s_waitcnt vmcnt(1)" ::: "memory");   // A0,A1,B0(t) valid
        __builtin_amdgcn_s_barrier();
#pragma unroll
        for (int m = 0; m < 2; ++m) {
            a[m][0] = *(const bf16x8*)((const char*)AB + co + arow + m * 2048 + jq0);
            a[m][1] = *(const bf16x8*)((const char*)AB + co + arow + m * 2048 + jq1);
        }
#pragma unroll
        for (int n = 0; n < 4; ++n) {
            b[n][0] = *(const bf16x8*)((const char*)AB + co + brow + n * 2048 + jq0);
            b[n][1] = *(const bf16x8*)((const char*)AB + co + brow + n * 2048 + jq1);
        }
        STAGE(0); STAGE(1); STAGE(2); STAGE(3); STAGE(4);
        __builtin_amdgcn_s_setprio(1);
#pragma unroll
        for (int m = 0; m < 2; ++m)
#pragma unroll
            for (int n = 0; n < 4; ++n) {
                MFMA(acc[m][n], a[m][0], b[n][0]);
                MFMA(acc[m][n], a[m][1], b[n][1]);
            }
        __builtin_amdgcn_s_setprio(0);

        // ---------------- P1: A(m0-1) x B(n4-7)
        asm volatile("s_waitcnt vmcnt(5)" ::: "memory");   // B1(t) valid
        __builtin_amdgcn_s_barrier();
#pragma unroll
        for (int n = 0; n < 4; ++n) {
            b[n][0] = *(const bf16x8*)((const char*)AB + co + brow + (4 + n) * 2048 + jq0);
            b[n][1] = *(const bf16x8*)((const char*)AB + co + brow + (4 + n) * 2048 + jq1);
        }
        STAGE(5);
        __builtin_amdgcn_s_setprio(1);
#pragma unroll
        for (int m = 0; m < 2; ++m)
#pragma unroll
            for (int n = 0; n < 4; ++n) {
                MFMA(acc[m][4 + n], a[m][0], b[n][0]);
                MFMA(acc[m][4 + n], a[m][1], b[n][1]);
            }
        __builtin_amdgcn_s_setprio(0);
    }
#undef STAGE
#undef MFMA

    // ---- drain wrap prefetches while LDS is still owned
    asm volatile("s_waitcnt vmcnt(0)" ::: "memory");

    // ---- epilogue: one head per block.  col(n) = n*16 + l15
    const int which = bn >> 11;                // 0=q 1=k 2=v
    const int head = (bn >> 7) & (NHEAD - 1);
    const float qsc = (which == 0) ? 0.12751791525f : 1.0f;  // 1/sqrt(128)*log2e

#pragma unroll
    for (int m = 0; m < 2; ++m) {
#pragma unroll
        for (int reg = 0; reg < 4; ++reg) {
            int gm = bm + w * 32 + m * 16 + quad * 4 + reg;
            int b2 = gm >> 11, nseq = gm & (NN - 1);
            int bh = b2 * NHEAD + head;
            if (which == 2) {
#pragma unroll
                for (int n = 0; n < 8; ++n) {
                    int d = n * 16 + l15;
                    Vtp[((size_t)bh * DHEAD + d) * NN + nseq] = f2bf(acc[m][n][reg]);
                }
            } else {
                short* dst = (which == 0 ? Qp : Kp) + ((size_t)bh * NN + nseq) * DHEAD;
#pragma unroll
                for (int p = 0; p < 4; ++p) {
                    int d0 = p * 16 + l15;     // < 64
                    float c = cosT[(size_t)nseq * DHEAD + d0];
                    float s = sinT[(size_t)nseq * DHEAD + d0];
                    float e0 = acc[m][p][reg];
                    float e1 = acc[m][p + 4][reg];
                    dst[d0]      = f2bf((e0 * c - e1 * s) * qsc);
                    dst[d0 + 64] = f2bf((e1 * c + e0 * s) * qsc);
                }
            }
        }
    }
}

// ---------------------------------------------------------------------------
// Output projection GEMM (round-8 verbatim): 256x128 / BK=64 / 8-wave
// 2-phase pipeline, fp32 C epilogue.  Grid (16,16) = 256 blocks = 1/CU.
// ---------------------------------------------------------------------------
__global__ __launch_bounds__(512, 2) void gemm_out_256x128(
    const short* __restrict__ A, const short* __restrict__ Bw,
    float* __restrict__ Cp)
{
    __shared__ __align__(16) short AB[49152];   // 96 KB

    const int tid = threadIdx.x;
    const int w = tid >> 6;
    const int l = tid & 63;
    const int quad = l >> 4;
    const int l15 = l & 15;
    const int bn = blockIdx.x * 128;
    const int bm = blockIdx.y * 256;
    const int K = HIDDEN;

    const short* src[6];
    int ldst[6];
#pragma unroll
    for (int ld = 0; ld < 2; ++ld) {
        int chunk = ld * 512 + tid;
        int row = chunk >> 3;
        int j = (chunk & 7) ^ (row & 7);
        int coff = j * 8;
        src[ld]     = A + (size_t)(bm + row) * K + coff;
        src[2 + ld] = A + (size_t)(bm + 128 + row) * K + coff;
        ldst[ld]     = chunk * 16;
        ldst[2 + ld] = 16384 + chunk * 16;
    }
    {
        int row = tid >> 3;
        int j = (tid & 7) ^ (row & 7);
        int coff = j * 8;
        src[4] = Bw + (size_t)(bn + row) * K + coff;
        src[5] = Bw + (size_t)(bn + 64 + row) * K + coff;
        ldst[4] = 32768 + tid * 16;
        ldst[5] = 32768 + 8192 + tid * 16;
    }

    const int xj = l15 & 7;
    const int jq0 = ((0 * 4 + quad) ^ xj) * 16;
    const int jq1 = ((1 * 4 + quad) ^ xj) * 16;
    const int arow = (w * 32 + l15) * 128;
    const int brow = 32768 + l15 * 128;

    floatx4 acc[2][8];
#pragma unroll
    for (int i = 0; i < 2; ++i)
#pragma unroll
        for (int j = 0; j < 8; ++j) acc[i][j] = (floatx4){0.f, 0.f, 0.f, 0.f};

#pragma unroll
    for (int i = 0; i < 6; ++i)
        gload_lds16(src[i], (short*)((char*)AB + ldst[i]));

#define STAGE(i) gload_lds16(src[i] + kpf, (short*)((char*)AB + ldst[i] + so))
#define MFMA(d, x, y) d = __builtin_amdgcn_mfma_f32_16x16x32_bf16(x, y, d, 0, 0, 0)

    const int NT = K / 64;   // 32
#pragma unroll 1
    for (int t = 0; t < NT; ++t) {
        const int co = (t & 1) * 49152;
        const int so = co ^ 49152;
        int kpf = (t + 1) * 64;
        if (kpf == K) kpf = 0;

        bf16x8 a[2][2], b[4][2];

        // ---------------- P0
        asm volatile("s_waitcnt vmcnt(1)" ::: "memory");
        __builtin_amdgcn_s_barrier();
#pragma unroll
        for (int m = 0; m < 2; ++m) {
            a[m][0] = *(const bf16x8*)((const char*)AB + co + arow + m * 2048 + jq0);
            a[m][1] = *(const bf16x8*)((const char*)AB + co + arow + m * 2048 + jq1);
        }
#pragma unroll
        for (int n = 0; n < 4; ++n) {
            b[n][0] = *(const bf16x8*)((const char*)AB + co + brow + n * 2048 + jq0);
            b[n][1] = *(const bf16x8*)((const char*)AB + co + brow + n * 2048 + jq1);
        }
        STAGE(0); STAGE(1); STAGE(2); STAGE(3); STAGE(4);
        __builtin_amdgcn_s_setprio(1);
#pragma unroll
        for (int m = 0; m < 2; ++m)
#pragma unroll
            for (int n = 0; n < 4; ++n) {
                MFMA(acc[m][n], a[m][0], b[n][0]);
                MFMA(acc[m][n], a[m][1], b[n][1]);
            }
        __builtin_amdgcn_s_setprio(0);

        // ---------------- P1
        asm volatile("s_waitcnt vmcnt(5)" ::: "memory");
        __builtin_amdgcn_s_barrier();
#pragma unroll
        for (int n = 0; n < 4; ++n) {
            b[n][0] = *(const bf16x8*)((const char*)AB + co + brow + (4 + n) * 2048 + jq0);
            b[n][1] = *(const bf16x8*)((const char*)AB + co + brow + (4 + n) * 2048 + jq1);
        }
        STAGE(5);
        __builtin_amdgcn_s_setprio(1);
#pragma unroll
        for (int m = 0; m < 2; ++m)
#pragma unroll
            for (int n = 0; n < 4; ++n) {
                MFMA(acc[m][4 + n], a[m][0], b[n][0]);
                MFMA(acc[m][4 + n], a[m][1], b[n][1]);
            }
        __builtin_amdgcn_s_setprio(0);
    }
#undef STAGE
#undef MFMA

    asm volatile("s_waitcnt vmcnt(0)" ::: "memory");

#pragma unroll
    for (int m = 0; m < 2; ++m) {
#pragma unroll
        for (int reg = 0; reg < 4; ++reg) {
            int row = bm + w * 32 + m * 16 + quad * 4 + reg;
            float* crow = Cp + (size_t)row * HIDDEN + bn;
#pragma unroll
            for (int n = 0; n < 8; ++n)
                crow[n * 16 + l15] = acc[m][n][reg];
        }
    }
}

// ---------------------------------------------------------------------------
// MFMA flash attention R10: R9 (swapped QK^T, cvt_pk softmax) + TRIPLE-
// buffered K/V with counted vmcnt (never 0 in steady loop) + setprio around
// MFMA clusters (T5, attn +4-7% measured).
// Ledger (4 DMAs/thread/tile): prologue stages t0,t1 (8 out), vmcnt(4)
// validates t0.  Tile t: stage t+2 (8 out); compute; end vmcnt(4) drains
// t+1; barrier.  t=NT-2 ends vmcnt(0); t=NT-1 stages nothing -> 0
// outstanding at endpgm.  WAR: buf[(t+2)%3] last read at t-1, separated by
// t-1's end barrier.  LDS 3x(16+16)+36.9 = 132.9 KB -> 1 block/CU.
// ---------------------------------------------------------------------------
__global__ __launch_bounds__(512, 2) void attn_mfma8(
    const short* __restrict__ Qb, const short* __restrict__ Kb,
    const short* __restrict__ Vt, short* __restrict__ AOb)
{
    __shared__ __align__(16) short Ks[3][64 * 128];   // 48 KB, swz (s&15)^(row&15)
    __shared__ __align__(16) short Vs[3][128 * 64];   // 48 KB, swz (s&7)^(row&7)
    __shared__ __align__(16) short Ps[8][32][72];     // 36.9 KB bf16 [query][key]

    const int tid = threadIdx.x;       // 0..511
    const int w = tid >> 6;            // 0..7
    const int l = tid & 63;
    const int quad = l >> 4;
    const int l15 = l & 15;
    const int bh = blockIdx.y;
    const int qt = blockIdx.x * 256;

    const short* Qg = Qb + (size_t)bh * NN * DHEAD;
    const short* Kg = Kb + (size_t)bh * NN * DHEAD;
    const short* Vg = Vt + (size_t)bh * DHEAD * NN;

    // ---- Q fragments (registers, whole kernel)
    bf16x8 qf[2][4];
#pragma unroll
    for (int mi = 0; mi < 2; ++mi) {
        const short* qrow = Qg + (size_t)(qt + w * 32 + mi * 16 + l15) * DHEAD + quad * 8;
#pragma unroll
        for (int kc = 0; kc < 4; ++kc) qf[mi][kc] = *(const bf16x8*)(qrow + kc * 32);
    }

    // ---- staging addresses: 2 K-slots + 2 V-slots per thread
    const short* ksrc[2]; int kdst[2];
    const short* vsrc[2]; int vdst[2];
#pragma unroll
    for (int rr = 0; rr < 2; ++rr) {
        int s = rr * 512 + tid;
        {
            int row = s >> 4;
            int j = (s & 15) ^ (row & 15);
            ksrc[rr] = Kg + (size_t)row * DHEAD + j * 8;
            kdst[rr] = s * 8;
        }
        {
            int row = s >> 3;
            int c = (s & 7) ^ (row & 7);
            vsrc[rr] = Vg + (size_t)row * NN + c * 8;
            vdst[rr] = s * 8;
        }
    }

    floatx4 of[2][8];
#pragma unroll
    for (int mi = 0; mi < 2; ++mi)
#pragma unroll
        for (int dc = 0; dc < 8; ++dc) of[mi][dc] = (floatx4){0.f, 0.f, 0.f, 0.f};
    float ls[2] = {0.f, 0.f};

    // ---- prologue: stage tiles 0,1 into bufs 0,1; validate t0
#pragma unroll
    for (int rr = 0; rr < 2; ++rr) {
        gload_lds16(ksrc[rr], &Ks[0][0] + kdst[rr]);
        gload_lds16(vsrc[rr], &Vs[0][0] + vdst[rr]);
    }
#pragma unroll
    for (int rr = 0; rr < 2; ++rr) {
        gload_lds16(ksrc[rr] + (size_t)64 * DHEAD, &Ks[1][0] + kdst[rr]);
        gload_lds16(vsrc[rr] + 64, &Vs[1][0] + vdst[rr]);
    }
    asm volatile("s_waitcnt vmcnt(4)" ::: "memory");
    __builtin_amdgcn_s_barrier();

    const int NT = NN / 64;   // 32
#pragma unroll 1
    for (int t = 0; t < NT; ++t) {
        const int kt = t * 64;
        const int cb = t % 3;
        // ---- issue tile t+2 into buf[(t+2)%3]
        if (t + 2 < NT) {
            const int sb = (t + 2) % 3;
#pragma unroll
            for (int rr = 0; rr < 2; ++rr) {
                gload_lds16(ksrc[rr] + (size_t)(kt + 128) * DHEAD, &Ks[sb][0] + kdst[rr]);
                gload_lds16(vsrc[rr] + (kt + 128), &Vs[sb][0] + vdst[rr]);
            }
        }
        const short* kb = &Ks[cb][0];
        const short* vb = &Vs[cb][0];

        // ---- S^T = K @ Q^T (swapped operands): lane holds 4 consecutive keys
        floatx4 sf[2][4];
#pragma unroll
        for (int n16 = 0; n16 < 4; ++n16) {
            bf16x8 kf[4];
            const short* kbase = kb + (n16 * 16 + l15) * 128;
#pragma unroll
            for (int kc = 0; kc < 4; ++kc)
                kf[kc] = *(const bf16x8*)&kbase[((4 * kc + quad) ^ l15) * 8];
            __builtin_amdgcn_s_setprio(1);
#pragma unroll
            for (int mi = 0; mi < 2; ++mi) {
                floatx4 acc = (floatx4){0.f, 0.f, 0.f, 0.f};
#pragma unroll
                for (int kc = 0; kc < 4; ++kc)
                    acc = __builtin_amdgcn_mfma_f32_16x16x32_bf16(kf[kc], qf[mi][kc], acc, 0, 0, 0);
                sf[mi][n16] = acc;
            }
            __builtin_amdgcn_s_setprio(0);
        }

        // ---- softmax: p = exp2(s); lane-local l partial; pack 4 keys ->
        //      one ds_write_b64 at Ps[query][key]
#pragma unroll
        for (int mi = 0; mi < 2; ++mi)
#pragma unroll
            for (int n16 = 0; n16 < 4; ++n16) {
                float p0 = exp2f(sf[mi][n16][0]);
                float p1 = exp2f(sf[mi][n16][1]);
                float p2 = exp2f(sf[mi][n16][2]);
                float p3 = exp2f(sf[mi][n16][3]);
                ls[mi] += (p0 + p1) + (p2 + p3);
                unsigned u0, u1;
                asm("v_cvt_pk_bf16_f32 %0, %1, %2" : "=v"(u0) : "v"(p0), "v"(p1));
                asm("v_cvt_pk_bf16_f32 %0, %1, %2" : "=v"(u1) : "v"(p2), "v"(p3));
                uint2 uu; uu.x = u0; uu.y = u1;
                *(uint2*)&Ps[w][mi * 16 + l15][n16 * 16 + quad * 4] = uu;
            }

        // ---- P A-frags (same-wave LDS roundtrip; Ps[w] is wave-private)
        bf16x8 pa[2][2];
#pragma unroll
        for (int mi = 0; mi < 2; ++mi)
#pragma unroll
            for (int kc = 0; kc < 2; ++kc)
                pa[mi][kc] = *(const bf16x8*)&Ps[w][mi * 16 + l15][kc * 32 + quad * 8];

        // ---- O += P @ V
#pragma unroll
        for (int dc = 0; dc < 8; ++dc) {
            int row = dc * 16 + l15;
#pragma unroll
            for (int kc = 0; kc < 2; ++kc) {
                bf16x8 vf = *(const bf16x8*)&vb[row * 64 + (((kc * 4 + quad) ^ (row & 7)) * 8)];
                __builtin_amdgcn_s_setprio(1);
#pragma unroll
                for (int mi = 0; mi < 2; ++mi)
                    of[mi][dc] = __builtin_amdgcn_mfma_f32_16x16x32_bf16(
                                     pa[mi][kc], vf, of[mi][dc], 0, 0, 0);
                __builtin_amdgcn_s_setprio(0);
            }
        }

        // ---- counted drain: validate t+1 (t+2 stays in flight)
        if (t + 2 < NT) {
            asm volatile("s_waitcnt vmcnt(4)" ::: "memory");
        } else {
            asm volatile("s_waitcnt vmcnt(0)" ::: "memory");
        }
        __builtin_amdgcn_s_barrier();
    }

    // ---- finalize: reduce l across stride-16 lanes; redistribute
    const int b = bh >> 4, h = bh & (NHEAD - 1);
#pragma unroll
    for (int mi = 0; mi < 2; ++mi) {
        float s = ls[mi];
        s += __shfl_xor(s, 16, 64);
        s += __shfl_xor(s, 32, 64);
#pragma unroll
        for (int r = 0; r < 4; ++r) {
            float sr = __shfl(s, quad * 4 + r, 64);
            float inv = 1.0f / sr;
            int row = qt + w * 32 + mi * 16 + quad * 4 + r;
            short* dst = AOb + ((size_t)(b * NN + row)) * HIDDEN + h * DHEAD;
#pragma unroll
            for (int dc = 0; dc < 8; ++dc)
                dst[dc * 16 + l15] = f2bf(of[mi][dc][r] * inv);
        }
    }
}

// ---------------------------------------------------------------------------
extern "C" void kernel_launch(void* const* d_in, const int* in_sizes, int n_in,
                              void* d_out, int out_size, void* d_ws, size_t ws_size,
                              hipStream_t stream)
{
    const float* hs = (const float*)d_in[0];
    const float* cosT = (const float*)d_in[1];
    const float* sinT = (const float*)d_in[2];
    const float* wqkv = (const float*)d_in[3];
    const float* wo = (const float*)d_in[4];
    float* out = (float*)d_out;

    const size_t N_HS = (size_t)NB * NN * HIDDEN;
    const size_t N_WQ = (size_t)3 * HIDDEN * HIDDEN;
    const size_t N_WO = (size_t)HIDDEN * HIDDEN;
    const size_t SZ = (size_t)NB * NHEAD * NN * DHEAD;

    short* Ahs   = (short*)d_ws;
    short* Wqkvb = Ahs + N_HS;
    short* Wob   = Wqkvb + N_WQ;
    short* Qb    = Wob + N_WO;
    short* Kb    = Qb + SZ;
    short* Vtb   = Kb + SZ;
    short* AOb   = Vtb + SZ;

    {
        int n4a = (int)(N_HS / 4), n4b = (int)(N_WQ / 4), n4c = (int)(N_WO / 4);
        int total = n4a + n4b + n4c;
        cast_bf16_3<<<(total + 255) / 256, 256, 0, stream>>>(
            hs, wqkv, wo, Ahs, Wqkvb, Wob, n4a, n4b, n4c);
    }
    {
        dim3 grid(3 * HIDDEN / 128, NB * NN / 256);   // (48, 16) = 768 = 3x256
        gemm_qkv_256x128<<<grid, 512, 0, stream>>>(
            Ahs, Wqkvb, cosT, sinT, Qb, Kb, Vtb);
    }
    {
        dim3 grid(NN / 256, NB * NHEAD);   // (8, 32) = 256 blocks = 1/CU
        attn_mfma8<<<grid, 512, 0, stream>>>(Qb, Kb, Vtb, AOb);
    }
    {
        dim3 grid(HIDDEN / 128, NB * NN / 256);   // (16, 16) = 256 = 1/CU
        gemm_out_256x128<<<grid, 512, 0, stream>>>(AOb, Wob, out);
    }
}